// Round 8
// baseline (336.440 us; speedup 1.0000x reference)
//
#include <hip/hip_runtime.h>

#define D 16
#define EFD 8
#define NREP 64       // BN-stats replica buffers (breaks atomic same-line contention)
#define TSTRIDE 272   // Tt row: 256 T values (+pad); 272%32==16 -> benign aliasing

// ---------------- zero scratch (cnt arrays + all 3 BN stat slots) ----------------

__global__ void k_zero2(int* a, int na, float* b, int nb) {
    int i = blockIdx.x * 256 + threadIdx.x;
    if (i < na) a[i] = 0;
    if (i < nb) b[i] = 0.f;
}

// ---------------- rank: one atomic per edge per side; cnt becomes the histogram ----------------

__global__ void k_rank2(const int* __restrict__ src, const int* __restrict__ dst,
                        int* __restrict__ cntS, int* __restrict__ cntD,
                        int* __restrict__ rankS, int* __restrict__ rankD, int E_) {
    int e = blockIdx.x * 256 + threadIdx.x;
    if (e < E_) {
        rankS[e] = atomicAdd(&cntS[src[e]], 1);
        rankD[e] = atomicAdd(&cntD[dst[e]], 1);
    }
}

// ---------------- scans over cntS|cntD (both halves in one launch) ----------------

__global__ void k_scanA2(const int* __restrict__ cnt2, int* __restrict__ offs2,
                         int* __restrict__ bsum2, int n, int nScan) {
    __shared__ int s[1024];
    int half = blockIdx.x / nScan;
    int blk  = blockIdx.x % nScan;
    const int* c = cnt2 + (size_t)half * n;
    int* of = offs2 + (size_t)half * (n + 1);
    int* bs = bsum2 + half * 64;
    int i = blk * 1024 + threadIdx.x;
    int v = (i < n) ? c[i] : 0;
    s[threadIdx.x] = v;
    __syncthreads();
    for (int d = 1; d < 1024; d <<= 1) {
        int t = (threadIdx.x >= d) ? s[threadIdx.x - d] : 0;
        __syncthreads();
        s[threadIdx.x] += t;
        __syncthreads();
    }
    int incl = s[threadIdx.x];
    if (i < n) of[i] = incl - v;            // exclusive within chunk
    if (threadIdx.x == 1023) bs[blk] = incl;
}

// scanC with the 64-entry block-sum scan folded in (done redundantly per block)
__global__ void k_scanC2(int* __restrict__ offs2, const int* __restrict__ bsum2,
                         int n, int nScan, int total) {
    __shared__ int s[64];
    int half = blockIdx.x / nScan;
    int blk  = blockIdx.x % nScan;
    int* of = offs2 + (size_t)half * (n + 1);
    const int* bs = bsum2 + half * 64;
    if (threadIdx.x < 64) s[threadIdx.x] = (threadIdx.x < nScan) ? bs[threadIdx.x] : 0;
    __syncthreads();
    if (threadIdx.x < 64) {
        for (int d = 1; d < 64; d <<= 1) {
            int t = (threadIdx.x >= d) ? s[threadIdx.x - d] : 0;
            __syncthreads();
            s[threadIdx.x] += t;
            __syncthreads();
        }
    } else {
        for (int d = 1; d < 64; d <<= 1) { __syncthreads(); __syncthreads(); }
    }
    int base = (blk == 0) ? 0 : s[blk - 1];
    int i = blk * 1024 + threadIdx.x;
    if (i < n) of[i] += base;
    else if (i == n) of[n] = total;
}

// ---------------- fused place + edge-MLP + permInv: NO atomics ----------------

__global__ void k_place_he(const int* __restrict__ src, const int* __restrict__ dst,
                           const int* __restrict__ rankS, const int* __restrict__ rankD,
                           const int* __restrict__ offsS, const int* __restrict__ offsD,
                           const float* __restrict__ ea, const float* __restrict__ w1,
                           const float* __restrict__ b1,
                           float* __restrict__ hE, int* __restrict__ permInv, int E_) {
    __shared__ float w1s[EFD * D];
    __shared__ float b1s[D];
    if (threadIdx.x < EFD * D) w1s[threadIdx.x] = w1[threadIdx.x];
    if (threadIdx.x < D) b1s[threadIdx.x] = b1[threadIdx.x];
    __syncthreads();
    int e = blockIdx.x * 256 + threadIdx.x;
    if (e >= E_) return;
    int p = offsS[src[e]] + rankS[e];
    int q = offsD[dst[e]] + rankD[e];
    permInv[p] = q;
    const float4* a4 = (const float4*)(ea + (size_t)e * EFD);
    float4 x0 = a4[0], x1 = a4[1];
    float out[D];
#pragma unroll
    for (int o = 0; o < D; o++) {
        float s = b1s[o];
        s += x0.x * w1s[0 * D + o] + x0.y * w1s[1 * D + o] +
             x0.z * w1s[2 * D + o] + x0.w * w1s[3 * D + o] +
             x1.x * w1s[4 * D + o] + x1.y * w1s[5 * D + o] +
             x1.z * w1s[6 * D + o] + x1.w * w1s[7 * D + o];
        out[o] = tanhf(s);
    }
    float4* h4 = (float4*)(hE + (size_t)p * D);
#pragma unroll
    for (int v = 0; v < 4; v++)
        h4[v] = make_float4(out[v * 4 + 0], out[v * 4 + 1], out[v * 4 + 2], out[v * 4 + 3]);
}

// ---------------- per-layer FUSED, WAVE-LOCAL (no barriers): BN + T-tile + messages ----------------
// Each wave owns 4 nodes. Thread (jj,o): w2 rows 4jj..4jj+3 in 64 VGPRs; computes the
// wave's 4-node T tile into a wave-private Tt slice; bias projection stays in a register.
// BN stats reduced redundantly per wave + __shfl. Same-wave LDS write->read ordering is
// guaranteed by compiler lgkmcnt on the shared arrays.

__global__ void k_Tmsg(const float* __restrict__ hin, const float* __restrict__ statsPrev,
                       const float* __restrict__ gamma, const float* __restrict__ beta,
                       float* __restrict__ hout, const float* __restrict__ w2,
                       const float* __restrict__ b2, const float* __restrict__ hE,
                       const int* __restrict__ offsS, const int* __restrict__ permInv,
                       float* __restrict__ msg, int n, int useBN) {
    __shared__ float hs[16 * D];          // 16 nodes x 16 feat (wave-private quarters)
    __shared__ float Tt[16 * TSTRIDE];    // per-node T (wave-private quarters)
    int tid = threadIdx.x;
    int lane = tid & 63;
    int w = tid >> 6;                     // wave 0..3
    int jj = lane >> 4;                   // 0..3
    int o = lane & 15;
    int slotG = (w << 2) + jj;            // block-local node 0..15
    int base = blockIdx.x * 16;
    int node = base + slotG;
    float fn = (float)n;

    // BN constants (per-wave redundant reduction, no barrier)
    float mu = 0.f, rstd = 1.f, gm = 1.f, bt = 0.f;
    if (useBN) {
        float a = 0.f;
        int c = lane & 31;
#pragma unroll 8
        for (int r = 0; r < NREP; r++) a += statsPrev[r * 32 + c];
        float sm = __shfl(a, o);
        float s2 = __shfl(a, 16 + o);
        mu = sm / fn;
        float var = s2 / fn - mu * mu;
        rstd = rsqrtf(var + 1e-5f);
        gm = gamma[o]; bt = beta[o];
    }
    // staging: thread (jj,o) stages feature o of its own node
    float hv = 0.f;
    if (node < n) {
        float xin = hin[(size_t)node * D + o];
        if (useBN) {
            hv = tanhf((xin - mu) * rstd * gm + bt);
            hout[(size_t)node * D + o] = hv;
        } else {
            hv = xin;
        }
    }
    hs[slotG * D + o] = hv;

    // w2 columns for rows 4jj..4jj+3 (64 VGPRs, L1-resident loads)
    float w16[4][16];
#pragma unroll
    for (int r = 0; r < 4; r++)
#pragma unroll
        for (int i = 0; i < 16; i++)
            w16[r][i] = w2[(4 * jj + r) * 256 + i * 16 + o];

    const float4* hs4 = (const float4*)hs;
    // bias projection for OWN node (register-resident, b2 loads inline)
    float4 g0 = hs4[slotG * 4 + 0], g1 = hs4[slotG * 4 + 1];
    float4 g2 = hs4[slotG * 4 + 2], g3 = hs4[slotG * 4 + 3];
    float tb = g0.x * b2[0 * 16 + o]  + g0.y * b2[1 * 16 + o]
             + g0.z * b2[2 * 16 + o]  + g0.w * b2[3 * 16 + o]
             + g1.x * b2[4 * 16 + o]  + g1.y * b2[5 * 16 + o]
             + g1.z * b2[6 * 16 + o]  + g1.w * b2[7 * 16 + o]
             + g2.x * b2[8 * 16 + o]  + g2.y * b2[9 * 16 + o]
             + g2.z * b2[10 * 16 + o] + g2.w * b2[11 * 16 + o]
             + g3.x * b2[12 * 16 + o] + g3.y * b2[13 * 16 + o]
             + g3.z * b2[14 * 16 + o] + g3.w * b2[15 * 16 + o];

    // T tile for this wave's 4 nodes only (16 ds_read_b128/thread total)
#pragma unroll
    for (int nbl = 0; nbl < 4; nbl++) {
        int nb = (w << 2) + nbl;
        float4 h0 = hs4[nb * 4 + 0], h1 = hs4[nb * 4 + 1];
        float4 h2 = hs4[nb * 4 + 2], h3 = hs4[nb * 4 + 3];
#pragma unroll
        for (int r = 0; r < 4; r++) {
            float s = h0.x * w16[r][0]  + h0.y * w16[r][1]
                    + h0.z * w16[r][2]  + h0.w * w16[r][3]
                    + h1.x * w16[r][4]  + h1.y * w16[r][5]
                    + h1.z * w16[r][6]  + h1.w * w16[r][7]
                    + h2.x * w16[r][8]  + h2.y * w16[r][9]
                    + h2.z * w16[r][10] + h2.w * w16[r][11]
                    + h3.x * w16[r][12] + h3.y * w16[r][13]
                    + h3.z * w16[r][14] + h3.w * w16[r][15];
            Tt[nb * TSTRIDE + (4 * jj + r) * 16 + o] = s;
        }
    }

    // own T column from the wave-private Tt slice
    float tr[16];
#pragma unroll
    for (int j2 = 0; j2 < 16; j2++)
        tr[j2] = Tt[slotG * TSTRIDE + j2 * 16 + o];

    if (node >= n) return;
    int p0 = offsS[node], p1 = offsS[node + 1];
    for (int p = p0; p < p1; p++) {
        const float4* he4 = (const float4*)(hE + (size_t)p * D);
        float4 a0 = he4[0], a1 = he4[1], a2 = he4[2], a3 = he4[3];
        float a = tb
            + a0.x * tr[0]  + a0.y * tr[1]  + a0.z * tr[2]  + a0.w * tr[3]
            + a1.x * tr[4]  + a1.y * tr[5]  + a1.z * tr[6]  + a1.w * tr[7]
            + a2.x * tr[8]  + a2.y * tr[9]  + a2.z * tr[10] + a2.w * tr[11]
            + a3.x * tr[12] + a3.y * tr[13] + a3.z * tr[14] + a3.w * tr[15];
        int q = permInv[p];                 // dst-sorted slot
        msg[(size_t)q * D + o] = a;         // scattered 64B-row store (fire-and-forget)
    }
}

// ---------------- per-layer: dst aggregation (sequential msg read) + root + bias + BN stats ----------------

__global__ void k_agg(const float* __restrict__ h, const float* __restrict__ msg,
                      const int* __restrict__ offsD, const float* __restrict__ root_l,
                      const float* __restrict__ cbias, float* __restrict__ hpre,
                      float* __restrict__ statsR, int n) {
    __shared__ float rootS[D * D];
    __shared__ float red[256], red2[256];
    if (threadIdx.x < D * D) rootS[threadIdx.x] = root_l[threadIdx.x];
    __syncthreads();
    int slot = threadIdx.x >> 4, o = threadIdx.x & 15;
    int node = blockIdx.x * 16 + slot;
    float acc = 0.f;
    if (node < n) {
        int p0 = offsD[node], p1 = offsD[node + 1];
        float sum = 0.f;
        int p = p0;
        for (; p + 4 <= p1; p += 4) {           // unrolled: 4 independent loads in flight
            float a0 = msg[(size_t)(p + 0) * D + o];
            float a1 = msg[(size_t)(p + 1) * D + o];
            float a2 = msg[(size_t)(p + 2) * D + o];
            float a3 = msg[(size_t)(p + 3) * D + o];
            sum += (a0 + a1) + (a2 + a3);
        }
        for (; p < p1; p++) sum += msg[(size_t)p * D + o];
        float deg = (float)((p1 - p0) > 1 ? (p1 - p0) : 1);
        float r = cbias[o];
        const float* hr = h + (size_t)node * D;
#pragma unroll
        for (int i = 0; i < D; i++) r += hr[i] * rootS[i * D + o];
        acc = sum / deg + r;
        hpre[(size_t)node * D + o] = acc;
    }
    red[threadIdx.x] = acc;
    red2[threadIdx.x] = acc * acc;
    __syncthreads();
    for (int off = 128; off >= 16; off >>= 1) {
        if (threadIdx.x < off) {
            red[threadIdx.x] += red[threadIdx.x + off];
            red2[threadIdx.x] += red2[threadIdx.x + off];
        }
        __syncthreads();
    }
    if (threadIdx.x < 32) {
        float v = (threadIdx.x < 16) ? red[threadIdx.x] : red2[threadIdx.x - 16];
        atomicAdd(&statsR[(blockIdx.x & (NREP - 1)) * 32 + threadIdx.x], v);
    }
}

// ---------------- fused readout: final BN+tanh + hidden write + pool + MLP + log_softmax ----------------

__global__ void k_readout(const float* __restrict__ hpre, const float* __restrict__ statsR,
                          const float* __restrict__ gamma, const float* __restrict__ beta,
                          const int* __restrict__ lengths,
                          const float* __restrict__ w1, const float* __restrict__ b1,
                          const float* __restrict__ w2, const float* __restrict__ b2,
                          float* __restrict__ outHidden, float* __restrict__ outPooled,
                          float* __restrict__ fcOut, float* __restrict__ lsmOut,
                          int Gc, int n) {
    __shared__ int sl[512];
    __shared__ float sstats[32];
    int tid = threadIdx.x;
    int g = blockIdx.x;
    if (tid < 32) {
        float a = 0.f;
#pragma unroll 8
        for (int r = 0; r < NREP; r++) a += statsR[r * 32 + tid];
        sstats[tid] = a;
    }
    int v = (tid < Gc) ? lengths[tid] : 0;
    sl[tid] = v;
    __syncthreads();
    for (int d = 1; d < 512; d <<= 1) {
        int t = (tid >= d) ? sl[tid - d] : 0;
        __syncthreads();
        sl[tid] += t;
        __syncthreads();
    }
    int n1 = sl[g];
    int n0 = n1 - lengths[g];
    float fn = (float)n;
    int slot = tid >> 4, o = tid & 15;
    float mu = sstats[o] / fn;
    float var = sstats[16 + o] / fn - mu * mu;
    float rstd = rsqrtf(var + 1e-5f);
    float gm = gamma[o], bt = beta[o];
    float s = 0.f, mx = -3.402823466e38f, mn = 3.402823466e38f;
    for (int nd = n0 + slot; nd < n1; nd += 32) {
        float xin = hpre[(size_t)nd * D + o];
        float x = tanhf((xin - mu) * rstd * gm + bt);
        outHidden[(size_t)nd * D + o] = x;
        s += x;
        mx = fmaxf(mx, x);
        mn = fminf(mn, x);
    }
    __shared__ float rs[512], rmx[512], rmn[512];
    rs[tid] = s; rmx[tid] = mx; rmn[tid] = mn;
    __syncthreads();
    for (int off = 256; off >= 16; off >>= 1) {
        if (tid < off) {
            rs[tid] += rs[tid + off];
            rmx[tid] = fmaxf(rmx[tid], rmx[tid + off]);
            rmn[tid] = fminf(rmn[tid], rmn[tid + off]);
        }
        __syncthreads();
    }
    __shared__ float p64[64], t16[16], f10[10];
    __shared__ float mred, lred;
    if (tid < 16) {
        float cnt = fmaxf((float)(n1 - n0), 1.f);
        float sum = rs[tid];
        float* row = outPooled + (size_t)g * 64;
        float mean = sum / cnt;
        p64[tid] = mean;          row[tid] = mean;
        p64[16 + tid] = rmx[tid]; row[16 + tid] = rmx[tid];
        p64[32 + tid] = rmn[tid]; row[32 + tid] = rmn[tid];
        p64[48 + tid] = sum;      row[48 + tid] = sum;
    }
    __syncthreads();
    if (tid < 16) {
        float a = b1[tid];
        for (int k = 0; k < 64; k++) a += p64[k] * w1[k * 16 + tid];
        t16[tid] = tanhf(a);
    }
    __syncthreads();
    if (tid < 10) {
        float a = b2[tid];
        for (int oo = 0; oo < 16; oo++) a += t16[oo] * w2[oo * 10 + tid];
        f10[tid] = a;
        fcOut[(size_t)g * 10 + tid] = a;
    }
    __syncthreads();
    if (tid == 0) {
        float m = f10[0];
        for (int c = 1; c < 10; c++) m = fmaxf(m, f10[c]);
        float se = 0.f;
        for (int c = 0; c < 10; c++) se += expf(f10[c] - m);
        mred = m;
        lred = logf(se);
    }
    __syncthreads();
    if (tid < 10)
        lsmOut[(size_t)g * 10 + tid] = f10[tid] - mred - lred;
}

// ---------------- host ----------------

extern "C" void kernel_launch(void* const* d_in, const int* in_sizes, int n_in,
                              void* d_out, int out_size, void* d_ws, size_t ws_size,
                              hipStream_t stream) {
    const float* x    = (const float*)d_in[0];
    const float* ea   = (const float*)d_in[1];
    const float* ew1  = (const float*)d_in[2];
    const float* eb1  = (const float*)d_in[3];
    const float* ew2  = (const float*)d_in[4];
    const float* eb2  = (const float*)d_in[5];
    const float* root = (const float*)d_in[6];
    const float* cb   = (const float*)d_in[7];
    const float* gam  = (const float*)d_in[8];
    const float* bet  = (const float*)d_in[9];
    const float* f1w  = (const float*)d_in[10];
    const float* f1b  = (const float*)d_in[11];
    const float* f2w  = (const float*)d_in[12];
    const float* f2b  = (const float*)d_in[13];
    const int* eidx   = (const int*)d_in[14];
    const int* lens   = (const int*)d_in[15];

    int N  = in_sizes[0] / D;
    int E_ = in_sizes[1] / EFD;
    int Gc = in_sizes[15];
    const int* srcIdx = eidx;
    const int* dstIdx = eidx + E_;

    float* outHidden = (float*)d_out;
    float* outPooled = outHidden + (size_t)N * D;
    float* outFc     = outPooled + (size_t)Gc * 4 * D;
    float* outLsm    = outFc + (size_t)Gc * 10;

    char* wsp = (char*)d_ws;
    size_t off = 0;
    auto alloc = [&](size_t bytes) -> void* {
        void* p = wsp + off;
        off = (off + bytes + 255) & ~(size_t)255;
        return p;
    };
    int*   cnt2    = (int*)alloc((size_t)2 * N * 4);          // cntS | cntD
    int*   offs2   = (int*)alloc((size_t)2 * (N + 1) * 4);    // offsS | offsD
    int*   bsum2   = (int*)alloc(128 * 4);
    int*   rankS   = (int*)alloc((size_t)E_ * 4);
    int*   rankD   = (int*)alloc((size_t)E_ * 4);
    int*   permInv = (int*)alloc((size_t)E_ * 4);
    float* hE      = (float*)alloc((size_t)E_ * D * 4);
    float* msg     = (float*)alloc((size_t)E_ * D * 4);
    float* bufA    = (float*)alloc((size_t)N * D * 4);
    float* tmp     = (float*)alloc((size_t)N * D * 4);
    float* statsR3 = (float*)alloc((size_t)3 * NREP * 32 * 4); // one slot per layer

    int* offsS = offs2;
    int* offsD = offs2 + (N + 1);
    int nScan = (N + 1023) / 1024;

    k_zero2<<<(2 * N + 255) / 256, 256, 0, stream>>>(cnt2, 2 * N, statsR3, 3 * NREP * 32);
    k_rank2<<<(E_ + 255) / 256, 256, 0, stream>>>(srcIdx, dstIdx, cnt2, cnt2 + N,
                                                  rankS, rankD, E_);
    k_scanA2<<<2 * nScan, 1024, 0, stream>>>(cnt2, offs2, bsum2, N, nScan);
    k_scanC2<<<2 * nScan, 1024, 0, stream>>>(offs2, bsum2, N, nScan, E_);
    k_place_he<<<(E_ + 255) / 256, 256, 0, stream>>>(srcIdx, dstIdx, rankS, rankD,
                                                     offsS, offsD, ea, ew1, eb1,
                                                     hE, permInv, E_);

    for (int l = 0; l < 3; l++) {
        const float* hin   = (l == 0) ? x : tmp;   // x or hpre of prev layer
        const float* hroot = (l == 0) ? x : bufA;  // post-BN h for root term
        float* statsCur = statsR3 + (size_t)l * NREP * 32;
        const float* statsPrev = statsR3 + (size_t)(l - 1) * NREP * 32;
        k_Tmsg<<<(N + 15) / 16, 256, 0, stream>>>(
            hin, (l == 0) ? nullptr : statsPrev,
            (l == 0) ? nullptr : gam + (size_t)(l - 1) * 16,
            (l == 0) ? nullptr : bet + (size_t)(l - 1) * 16,
            bufA, ew2, eb2, hE, offsS, permInv, msg, N, (l == 0) ? 0 : 1);
        k_agg<<<(N + 15) / 16, 256, 0, stream>>>(hroot, msg, offsD,
                                                 root + (size_t)l * 256, cb + (size_t)l * 16,
                                                 tmp, statsCur, N);
    }

    k_readout<<<Gc, 512, 0, stream>>>(tmp, statsR3 + (size_t)2 * NREP * 32,
                                      gam + 32, bet + 32, lens, f1w, f1b, f2w, f2b,
                                      outHidden, outPooled, outFc, outLsm, Gc, N);
}

// Round 9
// 328.337 us; speedup vs baseline: 1.0247x; 1.0247x over previous
//
#include <hip/hip_runtime.h>

#define D 16
#define EFD 8
#define NREP 64       // BN-stats replica buffers (breaks atomic same-line contention)
#define TSTRIDE 272   // Tt row: 256 T values + 16 bias; 272%32==16 -> benign aliasing

// ---------------- zero scratch (cnt arrays + all 3 BN stat slots) ----------------

__global__ void k_zero2(int* a, int na, float* b, int nb) {
    int i = blockIdx.x * 256 + threadIdx.x;
    if (i < na) a[i] = 0;
    if (i < nb) b[i] = 0.f;
}

// ---------------- rank: one atomic per edge per side; cnt becomes the histogram ----------------

__global__ void k_rank2(const int* __restrict__ src, const int* __restrict__ dst,
                        int* __restrict__ cntS, int* __restrict__ cntD,
                        int* __restrict__ rankS, int* __restrict__ rankD, int E_) {
    int e = blockIdx.x * 256 + threadIdx.x;
    if (e < E_) {
        rankS[e] = atomicAdd(&cntS[src[e]], 1);
        rankD[e] = atomicAdd(&cntD[dst[e]], 1);
    }
}

// ---------------- scans over cntS|cntD (both halves in one launch) ----------------

__global__ void k_scanA2(const int* __restrict__ cnt2, int* __restrict__ offs2,
                         int* __restrict__ bsum2, int n, int nScan) {
    __shared__ int s[1024];
    int half = blockIdx.x / nScan;
    int blk  = blockIdx.x % nScan;
    const int* c = cnt2 + (size_t)half * n;
    int* of = offs2 + (size_t)half * (n + 1);
    int* bs = bsum2 + half * 64;
    int i = blk * 1024 + threadIdx.x;
    int v = (i < n) ? c[i] : 0;
    s[threadIdx.x] = v;
    __syncthreads();
    for (int d = 1; d < 1024; d <<= 1) {
        int t = (threadIdx.x >= d) ? s[threadIdx.x - d] : 0;
        __syncthreads();
        s[threadIdx.x] += t;
        __syncthreads();
    }
    int incl = s[threadIdx.x];
    if (i < n) of[i] = incl - v;            // exclusive within chunk
    if (threadIdx.x == 1023) bs[blk] = incl;
}

// scanC with the 64-entry block-sum scan folded in (done redundantly per block)
__global__ void k_scanC2(int* __restrict__ offs2, const int* __restrict__ bsum2,
                         int n, int nScan, int total) {
    __shared__ int s[64];
    int half = blockIdx.x / nScan;
    int blk  = blockIdx.x % nScan;
    int* of = offs2 + (size_t)half * (n + 1);
    const int* bs = bsum2 + half * 64;
    if (threadIdx.x < 64) s[threadIdx.x] = (threadIdx.x < nScan) ? bs[threadIdx.x] : 0;
    __syncthreads();
    if (threadIdx.x < 64) {
        for (int d = 1; d < 64; d <<= 1) {
            int t = (threadIdx.x >= d) ? s[threadIdx.x - d] : 0;
            __syncthreads();
            s[threadIdx.x] += t;
            __syncthreads();
        }
    } else {
        for (int d = 1; d < 64; d <<= 1) { __syncthreads(); __syncthreads(); }
    }
    int base = (blk == 0) ? 0 : s[blk - 1];
    int i = blk * 1024 + threadIdx.x;
    if (i < n) of[i] += base;
    else if (i == n) of[n] = total;
}

// ---------------- fused place + edge-MLP + permInv: NO atomics ----------------

__global__ void k_place_he(const int* __restrict__ src, const int* __restrict__ dst,
                           const int* __restrict__ rankS, const int* __restrict__ rankD,
                           const int* __restrict__ offsS, const int* __restrict__ offsD,
                           const float* __restrict__ ea, const float* __restrict__ w1,
                           const float* __restrict__ b1,
                           float* __restrict__ hE, int* __restrict__ permInv, int E_) {
    __shared__ float w1s[EFD * D];
    __shared__ float b1s[D];
    if (threadIdx.x < EFD * D) w1s[threadIdx.x] = w1[threadIdx.x];
    if (threadIdx.x < D) b1s[threadIdx.x] = b1[threadIdx.x];
    __syncthreads();
    int e = blockIdx.x * 256 + threadIdx.x;
    if (e >= E_) return;
    int p = offsS[src[e]] + rankS[e];
    int q = offsD[dst[e]] + rankD[e];
    permInv[p] = q;
    const float4* a4 = (const float4*)(ea + (size_t)e * EFD);
    float4 x0 = a4[0], x1 = a4[1];
    float out[D];
#pragma unroll
    for (int o = 0; o < D; o++) {
        float s = b1s[o];
        s += x0.x * w1s[0 * D + o] + x0.y * w1s[1 * D + o] +
             x0.z * w1s[2 * D + o] + x0.w * w1s[3 * D + o] +
             x1.x * w1s[4 * D + o] + x1.y * w1s[5 * D + o] +
             x1.z * w1s[6 * D + o] + x1.w * w1s[7 * D + o];
        out[o] = tanhf(s);
    }
    float4* h4 = (float4*)(hE + (size_t)p * D);
#pragma unroll
    for (int v = 0; v < 4; v++)
        h4[v] = make_float4(out[v * 4 + 0], out[v * 4 + 1], out[v * 4 + 2], out[v * 4 + 3]);
}

// ---------------- per-layer FUSED: [BN+tanh prev] + T-tile + messages (pipelined) ----------------
// r7 structure: thread (j,o) holds w2 column in 16 VGPRs; T tile via broadcast ds_read_b128.
// Degree loop software-pipelined 1 deep: permInv/hE for edge p+1 issued before consuming
// edge p; first edge's loads issued before the FMA-heavy T phase to hide cold latency.

__global__ void k_Tmsg(const float* __restrict__ hin, const float* __restrict__ statsPrev,
                       const float* __restrict__ gamma, const float* __restrict__ beta,
                       float* __restrict__ hout, const float* __restrict__ w2,
                       const float* __restrict__ b2, const float* __restrict__ hE,
                       const int* __restrict__ offsS, const int* __restrict__ permInv,
                       float* __restrict__ msg, int n, int useBN) {
    __shared__ float hs[16 * D];          // 16 nodes x 16 feat
    __shared__ float Tt[16 * TSTRIDE];    // [slot][j*16+o | 256+o]
    __shared__ float sstats[32];
    int tid = threadIdx.x;
    int j = tid >> 4, o = tid & 15;
    int base = blockIdx.x * 16;
    int node = base + j;                  // the node this thread will emit messages for
    float fn = (float)n;
    // edge range for own node (read early so the first-edge prefetch can start)
    int p0 = 0, p1 = 0;
    if (node < n) { p0 = offsS[node]; p1 = offsS[node + 1]; }
    // first-edge prefetch (overlaps the T-phase FMAs)
    int qPre = 0;
    float4 a0, a1, a2, a3;
    if (p0 < p1) {
        qPre = permInv[p0];
        const float4* he4 = (const float4*)(hE + (size_t)p0 * D);
        a0 = he4[0]; a1 = he4[1]; a2 = he4[2]; a3 = he4[3];
    }
    // per-thread weight columns in registers
    float w16[16], b16[16];
#pragma unroll
    for (int i = 0; i < 16; i++) w16[i] = w2[j * 256 + i * 16 + o];
#pragma unroll
    for (int i = 0; i < 16; i++) b16[i] = b2[i * 16 + o];
    if (useBN && tid < 32) {
        float a = 0.f;
#pragma unroll 8
        for (int r = 0; r < NREP; r++) a += statsPrev[r * 32 + tid];
        sstats[tid] = a;
    }
    __syncthreads();
    {   // stage h rows (apply BN+tanh of previous layer if needed); thread (j,o) covers node j
        float hv = 0.f;
        if (node < n) {
            float xin = hin[(size_t)node * D + o];
            if (useBN) {
                float mu = sstats[o] / fn;
                float var = sstats[16 + o] / fn - mu * mu;
                hv = tanhf((xin - mu) * rsqrtf(var + 1e-5f) * gamma[o] + beta[o]);
                hout[(size_t)node * D + o] = hv;
            } else {
                hv = xin;
            }
        }
        hs[tid] = hv;   // hs[j*16 + o]
    }
    __syncthreads();
    {   // T-tile: broadcast b128 reads of hs + register FMAs
        const float4* hs4 = (const float4*)hs;
#pragma unroll
        for (int nb = 0; nb < 16; nb++) {
            float4 h0 = hs4[nb * 4 + 0], h1 = hs4[nb * 4 + 1];
            float4 h2 = hs4[nb * 4 + 2], h3 = hs4[nb * 4 + 3];
            float s = h0.x * w16[0]  + h0.y * w16[1]  + h0.z * w16[2]  + h0.w * w16[3]
                    + h1.x * w16[4]  + h1.y * w16[5]  + h1.z * w16[6]  + h1.w * w16[7]
                    + h2.x * w16[8]  + h2.y * w16[9]  + h2.z * w16[10] + h2.w * w16[11]
                    + h3.x * w16[12] + h3.y * w16[13] + h3.z * w16[14] + h3.w * w16[15];
            Tt[nb * TSTRIDE + tid] = s;   // contiguous per wave: conflict-free
        }
        // bias projection for node j (thread (j,o) owns it)
        float4 h0 = hs4[j * 4 + 0], h1 = hs4[j * 4 + 1];
        float4 h2 = hs4[j * 4 + 2], h3 = hs4[j * 4 + 3];
        float s = h0.x * b16[0]  + h0.y * b16[1]  + h0.z * b16[2]  + h0.w * b16[3]
                + h1.x * b16[4]  + h1.y * b16[5]  + h1.z * b16[6]  + h1.w * b16[7]
                + h2.x * b16[8]  + h2.y * b16[9]  + h2.z * b16[10] + h2.w * b16[11]
                + h3.x * b16[12] + h3.y * b16[13] + h3.z * b16[14] + h3.w * b16[15];
        Tt[j * TSTRIDE + 256 + o] = s;
    }
    __syncthreads();
    {   // messages: thread (slot=j, o); T row in registers; 1-deep pipelined degree loop
        int slot = j;
        if (node >= n) return;
        float tr[16];
#pragma unroll
        for (int j2 = 0; j2 < 16; j2++) tr[j2] = Tt[slot * TSTRIDE + j2 * 16 + o];
        float tb = Tt[slot * TSTRIDE + 256 + o];
        int q = qPre;
        for (int p = p0; p < p1; p++) {
            float4 b0 = a0, b1 = a1, b2 = a2, b3 = a3;
            int qc = q;
            if (p + 1 < p1) {               // prefetch next edge before consuming current
                q = permInv[p + 1];
                const float4* n4 = (const float4*)(hE + (size_t)(p + 1) * D);
                a0 = n4[0]; a1 = n4[1]; a2 = n4[2]; a3 = n4[3];
            }
            float a = tb
                + b0.x * tr[0]  + b0.y * tr[1]  + b0.z * tr[2]  + b0.w * tr[3]
                + b1.x * tr[4]  + b1.y * tr[5]  + b1.z * tr[6]  + b1.w * tr[7]
                + b2.x * tr[8]  + b2.y * tr[9]  + b2.z * tr[10] + b2.w * tr[11]
                + b3.x * tr[12] + b3.y * tr[13] + b3.z * tr[14] + b3.w * tr[15];
            msg[(size_t)qc * D + o] = a;    // scattered 64B-row store (fire-and-forget)
        }
    }
}

// ---------------- per-layer: dst aggregation (sequential msg read) + root + bias + BN stats ----------------

__global__ void k_agg(const float* __restrict__ h, const float* __restrict__ msg,
                      const int* __restrict__ offsD, const float* __restrict__ root_l,
                      const float* __restrict__ cbias, float* __restrict__ hpre,
                      float* __restrict__ statsR, int n) {
    __shared__ float rootS[D * D];
    __shared__ float red[256], red2[256];
    if (threadIdx.x < D * D) rootS[threadIdx.x] = root_l[threadIdx.x];
    __syncthreads();
    int slot = threadIdx.x >> 4, o = threadIdx.x & 15;
    int node = blockIdx.x * 16 + slot;
    float acc = 0.f;
    if (node < n) {
        int p0 = offsD[node], p1 = offsD[node + 1];
        float sum = 0.f;
        int p = p0;
        for (; p + 4 <= p1; p += 4) {           // unrolled: 4 independent loads in flight
            float a0 = msg[(size_t)(p + 0) * D + o];
            float a1 = msg[(size_t)(p + 1) * D + o];
            float a2 = msg[(size_t)(p + 2) * D + o];
            float a3 = msg[(size_t)(p + 3) * D + o];
            sum += (a0 + a1) + (a2 + a3);
        }
        for (; p < p1; p++) sum += msg[(size_t)p * D + o];
        float deg = (float)((p1 - p0) > 1 ? (p1 - p0) : 1);
        float r = cbias[o];
        const float* hr = h + (size_t)node * D;
#pragma unroll
        for (int i = 0; i < D; i++) r += hr[i] * rootS[i * D + o];
        acc = sum / deg + r;
        hpre[(size_t)node * D + o] = acc;
    }
    red[threadIdx.x] = acc;
    red2[threadIdx.x] = acc * acc;
    __syncthreads();
    for (int off = 128; off >= 16; off >>= 1) {
        if (threadIdx.x < off) {
            red[threadIdx.x] += red[threadIdx.x + off];
            red2[threadIdx.x] += red2[threadIdx.x + off];
        }
        __syncthreads();
    }
    if (threadIdx.x < 32) {
        float v = (threadIdx.x < 16) ? red[threadIdx.x] : red2[threadIdx.x - 16];
        atomicAdd(&statsR[(blockIdx.x & (NREP - 1)) * 32 + threadIdx.x], v);
    }
}

// ---------------- fused readout: final BN+tanh + hidden write + pool + MLP + log_softmax ----------------

__global__ void k_readout(const float* __restrict__ hpre, const float* __restrict__ statsR,
                          const float* __restrict__ gamma, const float* __restrict__ beta,
                          const int* __restrict__ lengths,
                          const float* __restrict__ w1, const float* __restrict__ b1,
                          const float* __restrict__ w2, const float* __restrict__ b2,
                          float* __restrict__ outHidden, float* __restrict__ outPooled,
                          float* __restrict__ fcOut, float* __restrict__ lsmOut,
                          int Gc, int n) {
    __shared__ int sl[512];
    __shared__ float sstats[32];
    int tid = threadIdx.x;
    int g = blockIdx.x;
    if (tid < 32) {
        float a = 0.f;
#pragma unroll 8
        for (int r = 0; r < NREP; r++) a += statsR[r * 32 + tid];
        sstats[tid] = a;
    }
    int v = (tid < Gc) ? lengths[tid] : 0;
    sl[tid] = v;
    __syncthreads();
    for (int d = 1; d < 512; d <<= 1) {
        int t = (tid >= d) ? sl[tid - d] : 0;
        __syncthreads();
        sl[tid] += t;
        __syncthreads();
    }
    int n1 = sl[g];
    int n0 = n1 - lengths[g];
    float fn = (float)n;
    int slot = tid >> 4, o = tid & 15;
    float mu = sstats[o] / fn;
    float var = sstats[16 + o] / fn - mu * mu;
    float rstd = rsqrtf(var + 1e-5f);
    float gm = gamma[o], bt = beta[o];
    float s = 0.f, mx = -3.402823466e38f, mn = 3.402823466e38f;
    for (int nd = n0 + slot; nd < n1; nd += 32) {
        float xin = hpre[(size_t)nd * D + o];
        float x = tanhf((xin - mu) * rstd * gm + bt);
        outHidden[(size_t)nd * D + o] = x;
        s += x;
        mx = fmaxf(mx, x);
        mn = fminf(mn, x);
    }
    __shared__ float rs[512], rmx[512], rmn[512];
    rs[tid] = s; rmx[tid] = mx; rmn[tid] = mn;
    __syncthreads();
    for (int off = 256; off >= 16; off >>= 1) {
        if (tid < off) {
            rs[tid] += rs[tid + off];
            rmx[tid] = fmaxf(rmx[tid], rmx[tid + off]);
            rmn[tid] = fminf(rmn[tid], rmn[tid + off]);
        }
        __syncthreads();
    }
    __shared__ float p64[64], t16[16], f10[10];
    __shared__ float mred, lred;
    if (tid < 16) {
        float cnt = fmaxf((float)(n1 - n0), 1.f);
        float sum = rs[tid];
        float* row = outPooled + (size_t)g * 64;
        float mean = sum / cnt;
        p64[tid] = mean;          row[tid] = mean;
        p64[16 + tid] = rmx[tid]; row[16 + tid] = rmx[tid];
        p64[32 + tid] = rmn[tid]; row[32 + tid] = rmn[tid];
        p64[48 + tid] = sum;      row[48 + tid] = sum;
    }
    __syncthreads();
    if (tid < 16) {
        float a = b1[tid];
        for (int k = 0; k < 64; k++) a += p64[k] * w1[k * 16 + tid];
        t16[tid] = tanhf(a);
    }
    __syncthreads();
    if (tid < 10) {
        float a = b2[tid];
        for (int oo = 0; oo < 16; oo++) a += t16[oo] * w2[oo * 10 + tid];
        f10[tid] = a;
        fcOut[(size_t)g * 10 + tid] = a;
    }
    __syncthreads();
    if (tid == 0) {
        float m = f10[0];
        for (int c = 1; c < 10; c++) m = fmaxf(m, f10[c]);
        float se = 0.f;
        for (int c = 0; c < 10; c++) se += expf(f10[c] - m);
        mred = m;
        lred = logf(se);
    }
    __syncthreads();
    if (tid < 10)
        lsmOut[(size_t)g * 10 + tid] = f10[tid] - mred - lred;
}

// ---------------- host ----------------

extern "C" void kernel_launch(void* const* d_in, const int* in_sizes, int n_in,
                              void* d_out, int out_size, void* d_ws, size_t ws_size,
                              hipStream_t stream) {
    const float* x    = (const float*)d_in[0];
    const float* ea   = (const float*)d_in[1];
    const float* ew1  = (const float*)d_in[2];
    const float* eb1  = (const float*)d_in[3];
    const float* ew2  = (const float*)d_in[4];
    const float* eb2  = (const float*)d_in[5];
    const float* root = (const float*)d_in[6];
    const float* cb   = (const float*)d_in[7];
    const float* gam  = (const float*)d_in[8];
    const float* bet  = (const float*)d_in[9];
    const float* f1w  = (const float*)d_in[10];
    const float* f1b  = (const float*)d_in[11];
    const float* f2w  = (const float*)d_in[12];
    const float* f2b  = (const float*)d_in[13];
    const int* eidx   = (const int*)d_in[14];
    const int* lens   = (const int*)d_in[15];

    int N  = in_sizes[0] / D;
    int E_ = in_sizes[1] / EFD;
    int Gc = in_sizes[15];
    const int* srcIdx = eidx;
    const int* dstIdx = eidx + E_;

    float* outHidden = (float*)d_out;
    float* outPooled = outHidden + (size_t)N * D;
    float* outFc     = outPooled + (size_t)Gc * 4 * D;
    float* outLsm    = outFc + (size_t)Gc * 10;

    char* wsp = (char*)d_ws;
    size_t off = 0;
    auto alloc = [&](size_t bytes) -> void* {
        void* p = wsp + off;
        off = (off + bytes + 255) & ~(size_t)255;
        return p;
    };
    int*   cnt2    = (int*)alloc((size_t)2 * N * 4);          // cntS | cntD
    int*   offs2   = (int*)alloc((size_t)2 * (N + 1) * 4);    // offsS | offsD
    int*   bsum2   = (int*)alloc(128 * 4);
    int*   rankS   = (int*)alloc((size_t)E_ * 4);
    int*   rankD   = (int*)alloc((size_t)E_ * 4);
    int*   permInv = (int*)alloc((size_t)E_ * 4);
    float* hE      = (float*)alloc((size_t)E_ * D * 4);
    float* msg     = (float*)alloc((size_t)E_ * D * 4);
    float* bufA    = (float*)alloc((size_t)N * D * 4);
    float* tmp     = (float*)alloc((size_t)N * D * 4);
    float* statsR3 = (float*)alloc((size_t)3 * NREP * 32 * 4); // one slot per layer

    int* offsS = offs2;
    int* offsD = offs2 + (N + 1);
    int nScan = (N + 1023) / 1024;

    k_zero2<<<(2 * N + 255) / 256, 256, 0, stream>>>(cnt2, 2 * N, statsR3, 3 * NREP * 32);
    k_rank2<<<(E_ + 255) / 256, 256, 0, stream>>>(srcIdx, dstIdx, cnt2, cnt2 + N,
                                                  rankS, rankD, E_);
    k_scanA2<<<2 * nScan, 1024, 0, stream>>>(cnt2, offs2, bsum2, N, nScan);
    k_scanC2<<<2 * nScan, 1024, 0, stream>>>(offs2, bsum2, N, nScan, E_);
    k_place_he<<<(E_ + 255) / 256, 256, 0, stream>>>(srcIdx, dstIdx, rankS, rankD,
                                                     offsS, offsD, ea, ew1, eb1,
                                                     hE, permInv, E_);

    for (int l = 0; l < 3; l++) {
        const float* hin   = (l == 0) ? x : tmp;   // x or hpre of prev layer
        const float* hroot = (l == 0) ? x : bufA;  // post-BN h for root term
        float* statsCur = statsR3 + (size_t)l * NREP * 32;
        const float* statsPrev = statsR3 + (size_t)(l - 1) * NREP * 32;
        k_Tmsg<<<(N + 15) / 16, 256, 0, stream>>>(
            hin, (l == 0) ? nullptr : statsPrev,
            (l == 0) ? nullptr : gam + (size_t)(l - 1) * 16,
            (l == 0) ? nullptr : bet + (size_t)(l - 1) * 16,
            bufA, ew2, eb2, hE, offsS, permInv, msg, N, (l == 0) ? 0 : 1);
        k_agg<<<(N + 15) / 16, 256, 0, stream>>>(hroot, msg, offsD,
                                                 root + (size_t)l * 256, cb + (size_t)l * 16,
                                                 tmp, statsCur, N);
    }

    k_readout<<<Gc, 512, 0, stream>>>(tmp, statsR3 + (size_t)2 * NREP * 32,
                                      gam + 32, bet + 32, lens, f1w, f1b, f2w, f2b,
                                      outHidden, outPooled, outFc, outLsm, Gc, N);
}